// Round 5
// baseline (34664.880 us; speedup 1.0000x reference)
//
#include <hip/hip_runtime.h>
#include <stdint.h>

// DSNN bit-exact fp32. Locked-in facts:
//  - Reference is k-ascending single-accumulator fma: R1/R4 matched with
//    absmax 0.0. Any reordered/reprecisioned sum (R2 MFMA hi/lo) flips spike
//    decisions chaotically (absmax 511). => fp32, j-ascending, dense fmaf
//    with spike in {0.0,1.0} (bitwise == conditional add). No MFMA.
//  - L0 spike rate ~0.47 (h0 std ~11 vs thr 1) -> sparsity skipping is
//    worthless; dense is optimal. fma floor 13.9 ms @ 157.3 TF.
//  - R4: 1024-thr WG, LDS 139.8 KB -> 1 WG/CU, one barrier group, VALUBusy
//    53%. R5 change: 512-thr WG, ROWS=16, LDS 74 KB -> 2 WGs/CU, two
//    independent barrier groups to overlap barrier drains; unroll 8.

typedef __attribute__((ext_vector_type(4))) float f32x4;

#define ALPHA 0.9f
#define BETA 0.85f
#define NSTEPS 127
#define WGT 512
#define ROWS 16
#define CPAD 20     // spkbuf col stride (floats): 16 rows + 4 pad, 80 B (16B-aligned)
#define HPAD 516    // h0buf row stride (floats), 2064 B (16B-aligned)

// Update forms verbatim from R1/R4 (bit-exact-verified vs np reference).
#define LIF_L0(M, H, SP) { float _m = BETA * (M) + (H); \
    const bool _b = (_m - 1.0f) > 0.0f; (M) = _b ? 0.0f : _m; \
    (SP) = _b ? 1.0f : 0.0f; }
#define LIF_MID(S, M, A, SP) { (S) = ALPHA * (S) + (A); \
    float _m = BETA * (M) + (S); const bool _b = (_m - 1.0f) > 0.0f; \
    (M) = _b ? 0.0f : _m; (SP) = _b ? 1.0f : 0.0f; }
#define LIF_OUT(S, M, A) { (S) = ALPHA * (S) + (A); (M) = BETA * (M) + (S); }

__global__ __launch_bounds__(WGT, 4)
void dsnn_kernel(const float* __restrict__ x,
                 const float* __restrict__ W0,
                 const float* __restrict__ W1,
                 const float* __restrict__ W2,
                 float* __restrict__ out)
{
    __shared__ float spkbuf[512 * CPAD];   // 40.96 KB, [col][row] (x-stage, then spikes)
    __shared__ float h0buf[ROWS * HPAD];   // 33.02 KB, [row][col]

    const int t  = threadIdx.x;
    const int c4 = (t & 127) * 4;          // cols c4..c4+3
    const int g4 = (t >> 7) * 4;           // rows g4..g4+3 (wave-uniform)
    const int r0 = blockIdx.x * ROWS;

    // ---- stage x (pos/neg split) into spkbuf [i][row], i = 0..255 ----
    for (int k = t; k < 256 * ROWS; k += WGT) {
        const int i = k >> 4;
        const int r = k & 15;
        const float v = (i < 128) ? x[(size_t)(r0 + r) * 128 + i]
                                  : -x[(size_t)(r0 + r) * 128 + (i - 128)];
        spkbuf[i * CPAD + r] = fmaxf(v, 0.0f);
    }
    __syncthreads();

    float acc[4][4];   // [row r][col cc]

    // acc[r][cc] += buf[j][g4+r] * W[j][c4+cc], j ascending (bit-exact order)
    auto gemm = [&](const float* Wcol, int K) {
        #pragma unroll 8
        for (int j = 0; j < K; ++j) {
            const f32x4 s4 = *(const f32x4*)(spkbuf + j * CPAD + g4);   // wave-uniform bcast
            const f32x4 wv = *(const f32x4*)(Wcol + (size_t)j * 512);
            #pragma unroll
            for (int r = 0; r < 4; ++r) {
                acc[r][0] = fmaf(s4[r], wv.x, acc[r][0]);
                acc[r][1] = fmaf(s4[r], wv.y, acc[r][1]);
                acc[r][2] = fmaf(s4[r], wv.z, acc[r][2]);
                acc[r][3] = fmaf(s4[r], wv.w, acc[r][3]);
            }
        }
    };

    // ---- h0 = x @ W0 (time-invariant), park in LDS ----
    #pragma unroll
    for (int r = 0; r < 4; ++r)
        #pragma unroll
        for (int cc = 0; cc < 4; ++cc) acc[r][cc] = 0.0f;
    gemm(W0 + c4, 256);
    #pragma unroll
    for (int r = 0; r < 4; ++r) {
        f32x4 hv = { acc[r][0], acc[r][1], acc[r][2], acc[r][3] };
        *(f32x4*)(h0buf + (g4 + r) * HPAD + c4) = hv;
    }
    __syncthreads();   // all x-reads done before spkbuf is reused for spikes

    // ---- recurrent state in registers ----
    float m0[4][4], s1[4][4], m1[4][4], s2[4][4], m2[4][4];
    #pragma unroll
    for (int r = 0; r < 4; ++r)
        #pragma unroll
        for (int cc = 0; cc < 4; ++cc) {
            m0[r][cc] = 0.f; s1[r][cc] = 0.f; m1[r][cc] = 0.f;
            s2[r][cc] = 0.f; m2[r][cc] = 0.f;
        }

    float sarr[4][4];   // [cc][r] spike staging for transposed LDS write

    for (int step = 0; step < NSTEPS; ++step) {
        // ===== layer 0: m0 = BETA*m0 + h0; spike; reset; spikes -> spkbuf =====
        #pragma unroll
        for (int r = 0; r < 4; ++r) {
            const f32x4 hv = *(const f32x4*)(h0buf + (g4 + r) * HPAD + c4);
            LIF_L0(m0[r][0], hv.x, sarr[0][r]);
            LIF_L0(m0[r][1], hv.y, sarr[1][r]);
            LIF_L0(m0[r][2], hv.z, sarr[2][r]);
            LIF_L0(m0[r][3], hv.w, sarr[3][r]);
        }
        #pragma unroll
        for (int cc = 0; cc < 4; ++cc) {
            f32x4 sv = { sarr[cc][0], sarr[cc][1], sarr[cc][2], sarr[cc][3] };
            *(f32x4*)(spkbuf + (c4 + cc) * CPAD + g4) = sv;
        }
        __syncthreads();                       // A: L0 spikes visible

        // ===== layer 1: h1 = spk0 @ W1 =====
        #pragma unroll
        for (int r = 0; r < 4; ++r)
            #pragma unroll
            for (int cc = 0; cc < 4; ++cc) acc[r][cc] = 0.0f;
        gemm(W1 + c4, 512);
        __syncthreads();                       // B: all reads of L0 spikes done

        #pragma unroll
        for (int r = 0; r < 4; ++r) {
            LIF_MID(s1[r][0], m1[r][0], acc[r][0], sarr[0][r]);
            LIF_MID(s1[r][1], m1[r][1], acc[r][1], sarr[1][r]);
            LIF_MID(s1[r][2], m1[r][2], acc[r][2], sarr[2][r]);
            LIF_MID(s1[r][3], m1[r][3], acc[r][3], sarr[3][r]);
        }
        #pragma unroll
        for (int cc = 0; cc < 4; ++cc) {
            f32x4 sv = { sarr[cc][0], sarr[cc][1], sarr[cc][2], sarr[cc][3] };
            *(f32x4*)(spkbuf + (c4 + cc) * CPAD + g4) = sv;
        }
        __syncthreads();                       // C: L1 spikes visible

        // ===== layer 2: h2 = spk1 @ W2; s2,m2 update; no reset =====
        #pragma unroll
        for (int r = 0; r < 4; ++r)
            #pragma unroll
            for (int cc = 0; cc < 4; ++cc) acc[r][cc] = 0.0f;
        gemm(W2 + c4, 512);
        #pragma unroll
        for (int r = 0; r < 4; ++r) {
            LIF_OUT(s2[r][0], m2[r][0], acc[r][0]);
            LIF_OUT(s2[r][1], m2[r][1], acc[r][1]);
            LIF_OUT(s2[r][2], m2[r][2], acc[r][2]);
            LIF_OUT(s2[r][3], m2[r][3], acc[r][3]);
        }
        __syncthreads();                       // D: L1-spike reads done before next L0 write
    }

    // ---- write final m2 ----
    #pragma unroll
    for (int r = 0; r < 4; ++r) {
        f32x4 ov = { m2[r][0], m2[r][1], m2[r][2], m2[r][3] };
        *(f32x4*)(out + (size_t)(r0 + g4 + r) * 512 + c4) = ov;
    }
}

extern "C" void kernel_launch(void* const* d_in, const int* in_sizes, int n_in,
                              void* d_out, int out_size, void* d_ws, size_t ws_size,
                              hipStream_t stream) {
    const float* inputs = (const float*)d_in[0];   // 16384 x 128
    const float* W0     = (const float*)d_in[1];   // 256 x 512
    const float* W1     = (const float*)d_in[2];   // 512 x 512
    const float* W2     = (const float*)d_in[3];   // 512 x 512
    float* out          = (float*)d_out;           // 16384 x 512

    dim3 grid(16384 / ROWS);     // 1024 workgroups, 16 rows each
    dim3 block(WGT);
    dsnn_kernel<<<grid, block, 0, stream>>>(inputs, W0, W1, W2, out);
}